// Round 1
// baseline (166.764 us; speedup 1.0000x reference)
//
#include <hip/hip_runtime.h>
#include <cstdint>

#define N_NODES 8192
#define DIN 128
#define DOUT 128
#define MAXDEG 128                               // Poisson(32): P(deg>128) ~ 1e-18
#define EPS 1e-8f

#define MB_ROWS 64                               // adjacency rows per build block
#define MB_BLOCKS (N_NODES / MB_ROWS)            // 128
#define WPR (N_NODES / 32)                       // 256 u32 words per adjacency row
#define XW_ROWS 64                               // rows per xw block
#define XW_BLOCKS (N_NODES / XW_ROWS)            // 128

// workspace layout (bytes): [dis 32KB][deg 32KB][list(u16) 2MB][z16 2MB]
#define OFF_DEG  (N_NODES * 4)
#define OFF_LIST (OFF_DEG + N_NODES * 4)
#define OFF_Z16  (OFF_LIST + N_NODES * MAXDEG * 2)

static __device__ __forceinline__ uint16_t f2bf(float f) {
    uint32_t u = __float_as_uint(f);
    return (uint16_t)((u + 0x7fffu + ((u >> 16) & 1u)) >> 16);   // RNE
}
static __device__ __forceinline__ float bf2f(uint32_t bits16) {
    return __uint_as_float(bits16 << 16);
}

// ---------------------------------------------------------------------------
// Kernel 1 (fused): blocks [0,128): adjacency build + extract, entirely in LDS.
//   Block b owns rows [b*64, b*64+64) as a 64 KB LDS bitmask. It streams the
//   (L2-resident) src array, keeps edges whose src is in range via LDS
//   atomicOr (dedup), then popcount+scan extracts deg/dis/list in-block.
//   ZERO global atomics; the 8 MB mask never exists in global memory.
// blocks [128,256): z16 = bf16(x @ W^T), 64 rows per block (4 column-teams).
// ---------------------------------------------------------------------------
__global__ __launch_bounds__(512) void gcn_build(const int* __restrict__ ei, int E,
                                                 const float* __restrict__ x,
                                                 const float* __restrict__ W,
                                                 uint16_t* __restrict__ z16,
                                                 float* __restrict__ dis,
                                                 int* __restrict__ deg,
                                                 uint16_t* __restrict__ list) {
    __shared__ uint32_t shbuf[MB_ROWS * WPR];    // 64 KB (xw role reuses 32 KB as float)
    int t = threadIdx.x;

    if ((int)blockIdx.x < MB_BLOCKS) {
        // ---------------- adjacency-slice role ----------------
        int mb = blockIdx.x;
        int r0 = mb * MB_ROWS;
        uint32_t (*lm)[WPR] = (uint32_t(*)[WPR])shbuf;

        // init: zero with the diagonal (self-loop) bit folded in -> no race
        // word w: local row r = w>>8, word-in-row wir = w&255.
        // diag word of row r is (r0+r)>>5 = mb*2 + (r>>5).
        int diag_base = mb * 2;
        for (int w4 = t; w4 < MB_ROWS * WPR / 4; w4 += 512) {
            uint32_t w0 = w4 * 4;
            uint32_t vals[4];
#pragma unroll
            for (int k = 0; k < 4; k++) {
                uint32_t w = w0 + k;
                uint32_t r = w >> 8;
                uint32_t wir = w & 255u;
                vals[k] = (wir == (uint32_t)(diag_base + (int)(r >> 5)))
                              ? (1u << ((r0 + r) & 31)) : 0u;
            }
            ((uint4*)shbuf)[w4] = make_uint4(vals[0], vals[1], vals[2], vals[3]);
        }
        __syncthreads();

        // stream all src values (int4-vectorized, L2-resident broadcast);
        // in-range edges (P=1/128) load dst and set the bit with an LDS atomic
        const int4* s4 = (const int4*)ei;
        const int* dsts = ei + E;
        for (int i4 = t; i4 < E / 4; i4 += 512) {
            int4 v = s4[i4];
            int base = i4 * 4;
            unsigned r;
            r = (unsigned)(v.x - r0);
            if (r < MB_ROWS) { int dd = dsts[base];     atomicOr(&lm[r][dd >> 5], 1u << (dd & 31)); }
            r = (unsigned)(v.y - r0);
            if (r < MB_ROWS) { int dd = dsts[base + 1]; atomicOr(&lm[r][dd >> 5], 1u << (dd & 31)); }
            r = (unsigned)(v.z - r0);
            if (r < MB_ROWS) { int dd = dsts[base + 2]; atomicOr(&lm[r][dd >> 5], 1u << (dd & 31)); }
            r = (unsigned)(v.w - r0);
            if (r < MB_ROWS) { int dd = dsts[base + 3]; atomicOr(&lm[r][dd >> 5], 1u << (dd & 31)); }
        }
        __syncthreads();

        // extract: wave per row, 8 rows per wave. popcount + wave prefix scan
        int wave = t >> 6, lane = t & 63;
        for (int rr = 0; rr < MB_ROWS / 8; rr++) {
            int r = wave * (MB_ROWS / 8) + rr;
            int row = r0 + r;
            uint4 w = ((const uint4*)lm[r])[lane];   // words 4*lane .. 4*lane+3
            uint32_t wa[4] = {w.x, w.y, w.z, w.w};
            int c = __popc(w.x) + __popc(w.y) + __popc(w.z) + __popc(w.w);

            int sum = c;                             // inclusive wave scan (width 64)
            for (int off = 1; off < 64; off <<= 1) {
                int v = __shfl_up(sum, off, 64);
                if (lane >= off) sum += v;
            }
            int excl = sum - c;
            if (lane == 63) {
                deg[row] = sum;
                dis[row] = rsqrtf((float)sum + EPS);
            }

            uint16_t* lrow = list + (size_t)row * MAXDEG;
            int bbase = lane * 128;                  // first bit index of this lane
            int pos = excl;
#pragma unroll
            for (int k = 0; k < 4; k++) {
                uint32_t m = wa[k];
                while (m) {
                    int b = __ffs(m) - 1;
                    m &= m - 1;
                    if (pos < MAXDEG) lrow[pos] = (uint16_t)(bbase + k * 32 + b);
                    pos++;
                }
            }
        }
        return;
    }

    // ---------------- xw role: 4 column-teams of 128; team h does 16 rows ----
    int bb = blockIdx.x - MB_BLOCKS;
    int col = t & 127;
    int team = t >> 7;                               // 0..3
    int row0 = bb * XW_ROWS + team * 16;
    float (*xl)[DIN] = (float(*)[DIN])shbuf;         // 32 KB of the 64 KB buffer

    for (int rr = 0; rr < 16; rr++)
        xl[team * 16 + rr][col] = x[(size_t)(row0 + rr) * DIN + col];
    __syncthreads();

    float acc[16];
#pragma unroll
    for (int rr = 0; rr < 16; rr++) acc[rr] = 0.f;

    const float* wrow = W + (size_t)col * DIN;
    for (int d = 0; d < DIN; d += 4) {
        float4 wv = *(const float4*)(wrow + d);
#pragma unroll
        for (int rr = 0; rr < 16; rr++) {
            const float* xr = &xl[team * 16 + rr][d];   // wave-uniform b128 broadcast
            acc[rr] += xr[0] * wv.x + xr[1] * wv.y + xr[2] * wv.z + xr[3] * wv.w;
        }
    }
#pragma unroll
    for (int rr = 0; rr < 16; rr++)
        z16[(size_t)(row0 + rr) * DOUT + col] = f2bf(acc[rr]);
}

// ---------------------------------------------------------------------------
// Kernel 2: out[i][c] = b[c] + dis_i * sum_{j in row i} dis_j * z[j][c]
// (self loop is already in the list). One wave per row, 4 rows per block.
// UNCHANGED from previous round for attribution.
// ---------------------------------------------------------------------------
__global__ __launch_bounds__(256) void gcn_agg(const int* __restrict__ deg,
                                               const float* __restrict__ dis,
                                               const uint16_t* __restrict__ list,
                                               const uint16_t* __restrict__ z16,
                                               const float* __restrict__ bias,
                                               float* __restrict__ out) {
    int row  = blockIdx.x * 4 + (threadIdx.x >> 6);
    int lane = threadIdx.x & 63;
    int n = min(deg[row], MAXDEG);

    const uint16_t* lrow = list + (size_t)row * MAXDEG;
    int j0 = (lane < n)      ? lrow[lane]      : 0;
    int j1 = (64 + lane < n) ? lrow[64 + lane] : 0;
    float d0 = dis[j0];
    float d1 = dis[j1];

    const uint32_t* zu = (const uint32_t*)z16;
    float a0 = 0.f, a1 = 0.f;
    for (int m = 0; m < n; m++) {
        int jj; float dd;
        if (m < 64) { jj = __shfl(j0, m, 64);      dd = __shfl(d0, m, 64); }
        else        { jj = __shfl(j1, m - 64, 64); dd = __shfl(d1, m - 64, 64); }
        uint32_t u = zu[(size_t)jj * 64 + lane];   // coalesced 256 B
        a0 += dd * bf2f(u & 0xffffu);
        a1 += dd * bf2f(u >> 16);
    }

    float di = dis[row];
    float2 bv = ((const float2*)bias)[lane];
    float2 o;
    o.x = bv.x + di * a0;
    o.y = bv.y + di * a1;
    ((float2*)out)[(size_t)row * 64 + lane] = o;
}

// ---------------------------------------------------------------------------
extern "C" void kernel_launch(void* const* d_in, const int* in_sizes, int n_in,
                              void* d_out, int out_size, void* d_ws, size_t ws_size,
                              hipStream_t stream) {
    const float* x  = (const float*)d_in[0];
    const int*   ei = (const int*)d_in[1];
    const float* W  = (const float*)d_in[2];
    const float* b  = (const float*)d_in[3];
    float* out = (float*)d_out;

    int E = in_sizes[1] / 2;

    float*    dis  = (float*)   d_ws;
    int*      deg  = (int*)     ((char*)d_ws + OFF_DEG);
    uint16_t* list = (uint16_t*)((char*)d_ws + OFF_LIST);
    uint16_t* z16  = (uint16_t*)((char*)d_ws + OFF_Z16);

    // adjacency build+extract (LDS bitmask, no global atomics)  ||  x@W^T
    gcn_build<<<MB_BLOCKS + XW_BLOCKS, 512, 0, stream>>>(ei, E, x, W, z16, dis, deg, list);

    gcn_agg<<<N_NODES / 4, 256, 0, stream>>>(deg, dis, list, z16, b, out);
}

// Round 2
// 123.952 us; speedup vs baseline: 1.3454x; 1.3454x over previous
//
#include <hip/hip_runtime.h>
#include <cstdint>

#define N_NODES 8192
#define DIN 128
#define DOUT 128
#define MAXDEG 128                               // Poisson(32): P(deg>128) ~ 1e-18
#define EPS 1e-8f

#define MB_ROWS 64                               // adjacency rows per build block
#define MB_BLOCKS (N_NODES / MB_ROWS)            // 128
#define WPR (N_NODES / 32)                       // 256 u32 words per adjacency row
#define XW_ROWS 64                               // rows per xw block
#define XW_BLOCKS (N_NODES / XW_ROWS)            // 128

// workspace layout (bytes): [dis 32KB][deg 32KB][list(u16) 2MB][z16 2MB]
#define OFF_DEG  (N_NODES * 4)
#define OFF_LIST (OFF_DEG + N_NODES * 4)
#define OFF_Z16  (OFF_LIST + N_NODES * MAXDEG * 2)

static __device__ __forceinline__ uint16_t f2bf(float f) {
    uint32_t u = __float_as_uint(f);
    return (uint16_t)((u + 0x7fffu + ((u >> 16) & 1u)) >> 16);   // RNE
}
static __device__ __forceinline__ float bf2f(uint32_t bits16) {
    return __uint_as_float(bits16 << 16);
}

// ---------------------------------------------------------------------------
// Kernel 1 (fused): blocks [0,128): adjacency build + extract, entirely in LDS.
//   Block b owns rows [b*64, b*64+64) as a 64 KB LDS bitmask. It streams BOTH
//   src and dst as coalesced int4 (prefetched one iteration ahead); in-range
//   edges set a bit with a fire-and-forget LDS atomicOr (ds_or_b32, no return,
//   no wait) -> zero dependent-gather latency inside divergent branches.
// blocks [128,256): z16 = bf16(x @ W^T), 64 rows per block (4 column-teams).
// ---------------------------------------------------------------------------
__global__ __launch_bounds__(512) void gcn_build(const int* __restrict__ ei, int E,
                                                 const float* __restrict__ x,
                                                 const float* __restrict__ W,
                                                 uint16_t* __restrict__ z16,
                                                 float* __restrict__ dis,
                                                 int* __restrict__ deg,
                                                 uint16_t* __restrict__ list) {
    __shared__ uint32_t shbuf[MB_ROWS * WPR];    // 64 KB (xw role reuses 32 KB as float)
    int t = threadIdx.x;

    if ((int)blockIdx.x < MB_BLOCKS) {
        // ---------------- adjacency-slice role ----------------
        int mb = blockIdx.x;
        int r0 = mb * MB_ROWS;
        uint32_t (*lm)[WPR] = (uint32_t(*)[WPR])shbuf;

        // init: zero with the diagonal (self-loop) bit folded in -> no race
        int diag_base = mb * 2;
        for (int w4 = t; w4 < MB_ROWS * WPR / 4; w4 += 512) {
            uint32_t w0 = w4 * 4;
            uint32_t vals[4];
#pragma unroll
            for (int k = 0; k < 4; k++) {
                uint32_t w = w0 + k;
                uint32_t r = w >> 8;
                uint32_t wir = w & 255u;
                vals[k] = (wir == (uint32_t)(diag_base + (int)(r >> 5)))
                              ? (1u << ((r0 + r) & 31)) : 0u;
            }
            ((uint4*)shbuf)[w4] = make_uint4(vals[0], vals[1], vals[2], vals[3]);
        }
        __syncthreads();

        // stream src AND dst (both int4-coalesced, L2-resident), prefetched.
        // Branch bodies are pure ds_or_b32 -> no vmcnt wait in divergent code.
        const int4* s4 = (const int4*)ei;
        const int4* d4 = (const int4*)(ei + E);
        int nIter = E >> 2;
        int4 vs, vd;
        int i4 = t;
        if (i4 < nIter) { vs = s4[i4]; vd = d4[i4]; }
        while (i4 < nIter) {
            int4 cs = vs, cd = vd;
            int nxt = i4 + 512;
            if (nxt < nIter) { vs = s4[nxt]; vd = d4[nxt]; }   // wave-uniform branch
            unsigned r;
            r = (unsigned)(cs.x - r0);
            if (r < MB_ROWS) atomicOr(&lm[r][cd.x >> 5], 1u << (cd.x & 31));
            r = (unsigned)(cs.y - r0);
            if (r < MB_ROWS) atomicOr(&lm[r][cd.y >> 5], 1u << (cd.y & 31));
            r = (unsigned)(cs.z - r0);
            if (r < MB_ROWS) atomicOr(&lm[r][cd.z >> 5], 1u << (cd.z & 31));
            r = (unsigned)(cs.w - r0);
            if (r < MB_ROWS) atomicOr(&lm[r][cd.w >> 5], 1u << (cd.w & 31));
            i4 = nxt;
        }
        // tail (E % 4)
        int rem = E & 3;
        if (t < rem) {
            int base = E & ~3;
            int s = ei[base + t], dd = ei[E + base + t];
            unsigned r = (unsigned)(s - r0);
            if (r < MB_ROWS) atomicOr(&lm[r][dd >> 5], 1u << (dd & 31));
        }
        __syncthreads();

        // extract: wave per row, 8 rows per wave. popcount + wave prefix scan
        int wave = t >> 6, lane = t & 63;
        for (int rr = 0; rr < MB_ROWS / 8; rr++) {
            int r = wave * (MB_ROWS / 8) + rr;
            int row = r0 + r;
            uint4 w = ((const uint4*)lm[r])[lane];   // words 4*lane .. 4*lane+3
            uint32_t wa[4] = {w.x, w.y, w.z, w.w};
            int c = __popc(w.x) + __popc(w.y) + __popc(w.z) + __popc(w.w);

            int sum = c;                             // inclusive wave scan (width 64)
            for (int off = 1; off < 64; off <<= 1) {
                int v = __shfl_up(sum, off, 64);
                if (lane >= off) sum += v;
            }
            int excl = sum - c;
            if (lane == 63) {
                deg[row] = sum;
                dis[row] = rsqrtf((float)sum + EPS);
            }

            uint16_t* lrow = list + (size_t)row * MAXDEG;
            int bbase = lane * 128;                  // first bit index of this lane
            int pos = excl;
#pragma unroll
            for (int k = 0; k < 4; k++) {
                uint32_t m = wa[k];
                while (m) {
                    int b = __ffs(m) - 1;
                    m &= m - 1;
                    if (pos < MAXDEG) lrow[pos] = (uint16_t)(bbase + k * 32 + b);
                    pos++;
                }
            }
        }
        return;
    }

    // ---------------- xw role: 4 column-teams of 128; team h does 16 rows ----
    int bb = blockIdx.x - MB_BLOCKS;
    int col = t & 127;
    int team = t >> 7;                               // 0..3
    int row0 = bb * XW_ROWS + team * 16;
    float (*xl)[DIN] = (float(*)[DIN])shbuf;         // 32 KB of the 64 KB buffer

    for (int rr = 0; rr < 16; rr++)
        xl[team * 16 + rr][col] = x[(size_t)(row0 + rr) * DIN + col];
    __syncthreads();

    float acc[16];
#pragma unroll
    for (int rr = 0; rr < 16; rr++) acc[rr] = 0.f;

    const float* wrow = W + (size_t)col * DIN;
    for (int d = 0; d < DIN; d += 4) {
        float4 wv = *(const float4*)(wrow + d);
#pragma unroll
        for (int rr = 0; rr < 16; rr++) {
            const float* xr = &xl[team * 16 + rr][d];   // wave-uniform b128 broadcast
            acc[rr] += xr[0] * wv.x + xr[1] * wv.y + xr[2] * wv.z + xr[3] * wv.w;
        }
    }
#pragma unroll
    for (int rr = 0; rr < 16; rr++)
        z16[(size_t)(row0 + rr) * DOUT + col] = f2bf(acc[rr]);
}

// ---------------------------------------------------------------------------
// Kernel 2: out[i][c] = b[c] + dis_i * sum_{j in row i} dis_j * z[j][c]
// (self loop is already in the list). One wave per row, 4 rows per block.
// UNCHANGED for attribution.
// ---------------------------------------------------------------------------
__global__ __launch_bounds__(256) void gcn_agg(const int* __restrict__ deg,
                                               const float* __restrict__ dis,
                                               const uint16_t* __restrict__ list,
                                               const uint16_t* __restrict__ z16,
                                               const float* __restrict__ bias,
                                               float* __restrict__ out) {
    int row  = blockIdx.x * 4 + (threadIdx.x >> 6);
    int lane = threadIdx.x & 63;
    int n = min(deg[row], MAXDEG);

    const uint16_t* lrow = list + (size_t)row * MAXDEG;
    int j0 = (lane < n)      ? lrow[lane]      : 0;
    int j1 = (64 + lane < n) ? lrow[64 + lane] : 0;
    float d0 = dis[j0];
    float d1 = dis[j1];

    const uint32_t* zu = (const uint32_t*)z16;
    float a0 = 0.f, a1 = 0.f;
    for (int m = 0; m < n; m++) {
        int jj; float dd;
        if (m < 64) { jj = __shfl(j0, m, 64);      dd = __shfl(d0, m, 64); }
        else        { jj = __shfl(j1, m - 64, 64); dd = __shfl(d1, m - 64, 64); }
        uint32_t u = zu[(size_t)jj * 64 + lane];   // coalesced 256 B
        a0 += dd * bf2f(u & 0xffffu);
        a1 += dd * bf2f(u >> 16);
    }

    float di = dis[row];
    float2 bv = ((const float2*)bias)[lane];
    float2 o;
    o.x = bv.x + di * a0;
    o.y = bv.y + di * a1;
    ((float2*)out)[(size_t)row * 64 + lane] = o;
}

// ---------------------------------------------------------------------------
extern "C" void kernel_launch(void* const* d_in, const int* in_sizes, int n_in,
                              void* d_out, int out_size, void* d_ws, size_t ws_size,
                              hipStream_t stream) {
    const float* x  = (const float*)d_in[0];
    const int*   ei = (const int*)d_in[1];
    const float* W  = (const float*)d_in[2];
    const float* b  = (const float*)d_in[3];
    float* out = (float*)d_out;

    int E = in_sizes[1] / 2;

    float*    dis  = (float*)   d_ws;
    int*      deg  = (int*)     ((char*)d_ws + OFF_DEG);
    uint16_t* list = (uint16_t*)((char*)d_ws + OFF_LIST);
    uint16_t* z16  = (uint16_t*)((char*)d_ws + OFF_Z16);

    // adjacency build+extract (LDS bitmask, no global atomics)  ||  x@W^T
    gcn_build<<<MB_BLOCKS + XW_BLOCKS, 512, 0, stream>>>(ei, E, x, W, z16, dis, deg, list);

    gcn_agg<<<N_NODES / 4, 256, 0, stream>>>(deg, dis, list, z16, b, out);
}

// Round 3
// 105.985 us; speedup vs baseline: 1.5735x; 1.1695x over previous
//
#include <hip/hip_runtime.h>
#include <cstdint>

#define N_NODES 8192
#define DIN 128
#define DOUT 128
#define MAXDEG 128                               // Poisson(32): P(deg>128) ~ 1e-18
#define EPS 1e-8f

#define MB_ROWS 64                               // adjacency rows per build block
#define MB_BLOCKS (N_NODES / MB_ROWS)            // 128
#define WPR (N_NODES / 32)                       // 256 u32 words per adjacency row
#define XW_ROWS 64                               // rows per xw block
#define XW_BLOCKS (N_NODES / XW_ROWS)            // 128

// workspace layout (bytes): [dis 32KB][deg 32KB][list(u16) 2MB][z16 2MB]
#define OFF_DEG  (N_NODES * 4)
#define OFF_LIST (OFF_DEG + N_NODES * 4)
#define OFF_Z16  (OFF_LIST + N_NODES * MAXDEG * 2)

static __device__ __forceinline__ uint16_t f2bf(float f) {
    uint32_t u = __float_as_uint(f);
    return (uint16_t)((u + 0x7fffu + ((u >> 16) & 1u)) >> 16);   // RNE
}
static __device__ __forceinline__ float bf2f(uint32_t bits16) {
    return __uint_as_float(bits16 << 16);
}

// ---------------------------------------------------------------------------
// Kernel 1 (fused): blocks [0,128): adjacency build + extract, entirely in LDS.
//   Block b owns rows [b*64, b*64+64) as a 64 KB LDS bitmask. Streams src+dst
//   as coalesced int4 in chunks of 4 pairs (16 edges/thread), double-buffered
//   in two named register sets -> 8 loads in flight across the processing of
//   the previous chunk (counted vmcnt, not 1-deep). Branch bodies are pure
//   fire-and-forget LDS atomicOr.
// blocks [128,256): z16 = bf16(x @ W^T), 64 rows per block (4 column-teams).
// ---------------------------------------------------------------------------
__global__ __launch_bounds__(512) void gcn_build(const int* __restrict__ ei, int E,
                                                 const float* __restrict__ x,
                                                 const float* __restrict__ W,
                                                 uint16_t* __restrict__ z16,
                                                 float* __restrict__ dis,
                                                 int* __restrict__ deg,
                                                 uint16_t* __restrict__ list) {
    __shared__ uint32_t shbuf[MB_ROWS * WPR];    // 64 KB (xw role reuses 32 KB as float)
    int t = threadIdx.x;

    if ((int)blockIdx.x < MB_BLOCKS) {
        // ---------------- adjacency-slice role ----------------
        int mb = blockIdx.x;
        int r0 = mb * MB_ROWS;
        uint32_t (*lm)[WPR] = (uint32_t(*)[WPR])shbuf;

        // init: zero with the diagonal (self-loop) bit folded in -> no race
        int diag_base = mb * 2;
        for (int w4 = t; w4 < MB_ROWS * WPR / 4; w4 += 512) {
            uint32_t w0 = w4 * 4;
            uint32_t vals[4];
#pragma unroll
            for (int k = 0; k < 4; k++) {
                uint32_t w = w0 + k;
                uint32_t r = w >> 8;
                uint32_t wir = w & 255u;
                vals[k] = (wir == (uint32_t)(diag_base + (int)(r >> 5)))
                              ? (1u << ((r0 + r) & 31)) : 0u;
            }
            ((uint4*)shbuf)[w4] = make_uint4(vals[0], vals[1], vals[2], vals[3]);
        }
        __syncthreads();

        // ---- edge stream: chunks of 4 int4-pairs, A/B register double-buffer
        const int4* s4 = (const int4*)ei;
        const int4* d4 = (const int4*)(ei + E);
        int nIter  = E >> 2;                     // int4 groups
        int nChunk = nIter >> 11;                // 4*512 groups per chunk

#define LOADC(S0,S1,S2,S3,D0,D1,D2,D3,c) do { int b_ = ((c) << 11) + t;       \
            S0 = s4[b_];        S1 = s4[b_ + 512];                             \
            S2 = s4[b_ + 1024]; S3 = s4[b_ + 1536];                            \
            D0 = d4[b_];        D1 = d4[b_ + 512];                             \
            D2 = d4[b_ + 1024]; D3 = d4[b_ + 1536]; } while (0)

#define PROC1(cs, cd) do { unsigned r_;                                        \
            r_ = (unsigned)(cs.x - r0);                                        \
            if (r_ < MB_ROWS) atomicOr(&lm[r_][cd.x >> 5], 1u << (cd.x & 31)); \
            r_ = (unsigned)(cs.y - r0);                                        \
            if (r_ < MB_ROWS) atomicOr(&lm[r_][cd.y >> 5], 1u << (cd.y & 31)); \
            r_ = (unsigned)(cs.z - r0);                                        \
            if (r_ < MB_ROWS) atomicOr(&lm[r_][cd.z >> 5], 1u << (cd.z & 31)); \
            r_ = (unsigned)(cs.w - r0);                                        \
            if (r_ < MB_ROWS) atomicOr(&lm[r_][cd.w >> 5], 1u << (cd.w & 31)); } while (0)

        int4 as0, as1, as2, as3, ad0, ad1, ad2, ad3;
        int4 bs0, bs1, bs2, bs3, bd0, bd1, bd2, bd3;

        if (nChunk > 0) LOADC(as0,as1,as2,as3, ad0,ad1,ad2,ad3, 0);
        for (int c = 0; c < nChunk; c += 2) {
            if (c + 1 < nChunk) LOADC(bs0,bs1,bs2,bs3, bd0,bd1,bd2,bd3, c + 1);
            PROC1(as0, ad0); PROC1(as1, ad1); PROC1(as2, ad2); PROC1(as3, ad3);
            if (c + 2 < nChunk) LOADC(as0,as1,as2,as3, ad0,ad1,ad2,ad3, c + 2);
            if (c + 1 < nChunk) {
                PROC1(bs0, bd0); PROC1(bs1, bd1); PROC1(bs2, bd2); PROC1(bs3, bd3);
            }
        }
        // remainder int4 groups (none at E=262144, kept for generality)
        for (int i4 = (nChunk << 11) + t; i4 < nIter; i4 += 512) {
            int4 cs = s4[i4], cd = d4[i4];
            PROC1(cs, cd);
        }
        // scalar tail (E % 4)
        int rem = E & 3;
        if (t < rem) {
            int base = E & ~3;
            int s = ei[base + t], dd = ei[E + base + t];
            unsigned r = (unsigned)(s - r0);
            if (r < MB_ROWS) atomicOr(&lm[r][dd >> 5], 1u << (dd & 31));
        }
#undef LOADC
#undef PROC1
        __syncthreads();

        // extract: wave per row, 8 rows per wave. popcount + wave prefix scan
        int wave = t >> 6, lane = t & 63;
        for (int rr = 0; rr < MB_ROWS / 8; rr++) {
            int r = wave * (MB_ROWS / 8) + rr;
            int row = r0 + r;
            uint4 w = ((const uint4*)lm[r])[lane];   // words 4*lane .. 4*lane+3
            uint32_t wa[4] = {w.x, w.y, w.z, w.w};
            int c = __popc(w.x) + __popc(w.y) + __popc(w.z) + __popc(w.w);

            int sum = c;                             // inclusive wave scan (width 64)
            for (int off = 1; off < 64; off <<= 1) {
                int v = __shfl_up(sum, off, 64);
                if (lane >= off) sum += v;
            }
            int excl = sum - c;
            if (lane == 63) {
                deg[row] = sum;
                dis[row] = rsqrtf((float)sum + EPS);
            }

            uint16_t* lrow = list + (size_t)row * MAXDEG;
            int bbase = lane * 128;                  // first bit index of this lane
            int pos = excl;
#pragma unroll
            for (int k = 0; k < 4; k++) {
                uint32_t m = wa[k];
                while (m) {
                    int b = __ffs(m) - 1;
                    m &= m - 1;
                    if (pos < MAXDEG) lrow[pos] = (uint16_t)(bbase + k * 32 + b);
                    pos++;
                }
            }
        }
        return;
    }

    // ---------------- xw role: 4 column-teams of 128; team h does 16 rows ----
    int bb = blockIdx.x - MB_BLOCKS;
    int col = t & 127;
    int team = t >> 7;                               // 0..3
    int row0 = bb * XW_ROWS + team * 16;
    float (*xl)[DIN] = (float(*)[DIN])shbuf;         // 32 KB of the 64 KB buffer

    for (int rr = 0; rr < 16; rr++)
        xl[team * 16 + rr][col] = x[(size_t)(row0 + rr) * DIN + col];
    __syncthreads();

    float acc[16];
#pragma unroll
    for (int rr = 0; rr < 16; rr++) acc[rr] = 0.f;

    const float* wrow = W + (size_t)col * DIN;
    for (int d = 0; d < DIN; d += 4) {
        float4 wv = *(const float4*)(wrow + d);
#pragma unroll
        for (int rr = 0; rr < 16; rr++) {
            const float* xr = &xl[team * 16 + rr][d];   // wave-uniform b128 broadcast
            acc[rr] += xr[0] * wv.x + xr[1] * wv.y + xr[2] * wv.z + xr[3] * wv.w;
        }
    }
#pragma unroll
    for (int rr = 0; rr < 16; rr++)
        z16[(size_t)(row0 + rr) * DOUT + col] = f2bf(acc[rr]);
}

// ---------------------------------------------------------------------------
// Kernel 2: out[i][c] = b[c] + dis_i * sum_{j in row i} dis_j * z[j][c]
// (self loop is already in the list). One wave per row, 4 rows per block.
// Inner loop split into a branch-free first-64 segment processed 2-at-a-time
// with independent accumulator pairs (2 gathers in flight, FMA chain broken).
// ---------------------------------------------------------------------------
__global__ __launch_bounds__(256) void gcn_agg(const int* __restrict__ deg,
                                               const float* __restrict__ dis,
                                               const uint16_t* __restrict__ list,
                                               const uint16_t* __restrict__ z16,
                                               const float* __restrict__ bias,
                                               float* __restrict__ out) {
    int row  = blockIdx.x * 4 + (threadIdx.x >> 6);
    int lane = threadIdx.x & 63;
    int n = min(deg[row], MAXDEG);

    const uint16_t* lrow = list + (size_t)row * MAXDEG;
    int j0 = (lane < n)      ? lrow[lane]      : 0;
    int j1 = (64 + lane < n) ? lrow[64 + lane] : 0;
    float d0 = dis[j0];
    float d1 = dis[j1];

    const uint32_t* zu = (const uint32_t*)z16;
    float a0 = 0.f, a1 = 0.f, c0 = 0.f, c1 = 0.f;
    int n0 = min(n, 64);
    int m = 0;
    for (; m + 2 <= n0; m += 2) {
        int   ja = __shfl(j0, m, 64);     float da = __shfl(d0, m, 64);
        int   jb = __shfl(j0, m + 1, 64); float db = __shfl(d0, m + 1, 64);
        uint32_t ua = zu[(size_t)ja * 64 + lane];   // coalesced 256 B
        uint32_t ub = zu[(size_t)jb * 64 + lane];
        a0 += da * bf2f(ua & 0xffffu);
        a1 += da * bf2f(ua >> 16);
        c0 += db * bf2f(ub & 0xffffu);
        c1 += db * bf2f(ub >> 16);
    }
    if (m < n0) {
        int   ja = __shfl(j0, m, 64); float da = __shfl(d0, m, 64);
        uint32_t ua = zu[(size_t)ja * 64 + lane];
        a0 += da * bf2f(ua & 0xffffu);
        a1 += da * bf2f(ua >> 16);
    }
    for (int m2 = 64; m2 < n; m2++) {               // rare (deg > 64)
        int   jb = __shfl(j1, m2 - 64, 64); float db = __shfl(d1, m2 - 64, 64);
        uint32_t ub = zu[(size_t)jb * 64 + lane];
        c0 += db * bf2f(ub & 0xffffu);
        c1 += db * bf2f(ub >> 16);
    }
    a0 += c0; a1 += c1;

    float di = dis[row];
    float2 bv = ((const float2*)bias)[lane];
    float2 o;
    o.x = bv.x + di * a0;
    o.y = bv.y + di * a1;
    ((float2*)out)[(size_t)row * 64 + lane] = o;
}

// ---------------------------------------------------------------------------
extern "C" void kernel_launch(void* const* d_in, const int* in_sizes, int n_in,
                              void* d_out, int out_size, void* d_ws, size_t ws_size,
                              hipStream_t stream) {
    const float* x  = (const float*)d_in[0];
    const int*   ei = (const int*)d_in[1];
    const float* W  = (const float*)d_in[2];
    const float* b  = (const float*)d_in[3];
    float* out = (float*)d_out;

    int E = in_sizes[1] / 2;

    float*    dis  = (float*)   d_ws;
    int*      deg  = (int*)     ((char*)d_ws + OFF_DEG);
    uint16_t* list = (uint16_t*)((char*)d_ws + OFF_LIST);
    uint16_t* z16  = (uint16_t*)((char*)d_ws + OFF_Z16);

    // adjacency build+extract (LDS bitmask, no global atomics)  ||  x@W^T
    gcn_build<<<MB_BLOCKS + XW_BLOCKS, 512, 0, stream>>>(ei, E, x, W, z16, dis, deg, list);

    gcn_agg<<<N_NODES / 4, 256, 0, stream>>>(deg, dis, list, z16, b, out);
}